// Round 1
// baseline (1106.204 us; speedup 1.0000x reference)
//
#include <hip/hip_runtime.h>

#define E    512
#define H    8
#define HD   64
#define TGT  512
#define SRC  2048
#define S1   2049
#define S1P  2112     // padded source length (33 chunks of 64)
#define NB   16
#define BH   128
#define NCH  33
#define PW   2120     // P row stride in shorts: 4240 B = 16B-aligned, bank-uniform

typedef __attribute__((ext_vector_type(8))) short short8;
typedef __attribute__((ext_vector_type(4))) float floatx4;

__device__ __forceinline__ unsigned short f2bf(float x) {
    unsigned u = __float_as_uint(x);
    u = (u + 0x7FFF + ((u >> 16) & 1)) >> 16;   // round-to-nearest-even
    return (unsigned short)u;
}

// ---------------------------------------------------------------------------
// fp32 -> bf16 conversion, 8 elements/thread
// ---------------------------------------------------------------------------
__global__ __launch_bounds__(256) void cvt_bf16(const float* __restrict__ src,
    unsigned short* __restrict__ dst, const int n8)
{
    const int i = blockIdx.x * 256 + threadIdx.x;
    if (i >= n8) return;
    const float4 f0 = ((const float4*)src)[(size_t)i * 2];
    const float4 f1 = ((const float4*)src)[(size_t)i * 2 + 1];
    unsigned short o[8] = {f2bf(f0.x), f2bf(f0.y), f2bf(f0.z), f2bf(f0.w),
                           f2bf(f1.x), f2bf(f1.y), f2bf(f1.z), f2bf(f1.w)};
    ((int4*)dst)[i] = *(int4*)o;
}

// ---------------------------------------------------------------------------
// in-projection: Y = (X @ W^T + bias) * scale, output bf16 in [b*H+h][row][hd]
// ---------------------------------------------------------------------------
__global__ __launch_bounds__(256) void proj_gemm(const unsigned short* __restrict__ X,
    const unsigned short* __restrict__ W, const float* __restrict__ bias,
    unsigned short* __restrict__ Y, const int ld, const float scale)
{
    __shared__ __align__(16) unsigned short As[128][72];
    __shared__ __align__(16) unsigned short Bs[64][72];
    const int tid  = threadIdx.x;
    const int c0   = blockIdx.x << 6;
    const int r0   = blockIdx.y << 7;
    const int w    = tid >> 6, lane = tid & 63, c = lane & 15, quad = lane >> 4;
    floatx4 acc[2][4] = {};
    for (int k0 = 0; k0 < E; k0 += 64) {
#pragma unroll
        for (int i = 0; i < 4; ++i) {
            const int idx = tid + (i << 8);
            const int r = idx >> 3, q = (idx & 7) << 3;
            *(int4*)&As[r][q] = *(const int4*)&X[(size_t)(r0 + r) * E + k0 + q];
        }
#pragma unroll
        for (int i = 0; i < 2; ++i) {
            const int idx = tid + (i << 8);
            const int r = idx >> 3, q = (idx & 7) << 3;
            *(int4*)&Bs[r][q] = *(const int4*)&W[(size_t)(c0 + r) * E + k0 + q];
        }
        __syncthreads();
#pragma unroll
        for (int kh = 0; kh < 2; ++kh) {
            short8 a0 = *(const short8*)&As[(w << 5) + c][(kh << 5) + (quad << 3)];
            short8 a1 = *(const short8*)&As[(w << 5) + 16 + c][(kh << 5) + (quad << 3)];
#pragma unroll
            for (int n = 0; n < 4; ++n) {
                short8 b = *(const short8*)&Bs[(n << 4) + c][(kh << 5) + (quad << 3)];
                acc[0][n] = __builtin_amdgcn_mfma_f32_16x16x32_bf16(a0, b, acc[0][n], 0, 0, 0);
                acc[1][n] = __builtin_amdgcn_mfma_f32_16x16x32_bf16(a1, b, acc[1][n], 0, 0, 0);
            }
        }
        __syncthreads();
    }
#pragma unroll
    for (int mt = 0; mt < 2; ++mt) {
#pragma unroll
        for (int reg = 0; reg < 4; ++reg) {
            const int rg = r0 + (w << 5) + (mt << 4) + (quad << 2) + reg;
            const int t = rg >> 4, b = rg & 15;
#pragma unroll
            for (int n = 0; n < 4; ++n) {
                const int col = c0 + (n << 4) + c;
                const int h = col >> 6, hd = col & 63;
                const float v = (acc[mt][n][reg] + bias[col]) * scale;
                Y[((size_t)(b * H + h) * ld + t) * HD + hd] = f2bf(v);
            }
        }
    }
}

// kbuf[bh][2048][hd] = bias_k; vtbuf[bh][hd][2048] = bias_v.
// Also zero the pad tail (s in [2049,2112)) of both buffers so the fused
// attention kernel never multiplies P=0 against uninitialized (potentially
// NaN/Inf) poison bytes.
__global__ void fill_bias(const float* __restrict__ bk, const float* __restrict__ bv,
                          unsigned short* __restrict__ kbuf, unsigned short* __restrict__ vtbuf)
{
    const int idx = blockIdx.x * 256 + threadIdx.x;   // 0..8191
    const int bh = idx >> 6, hd = idx & 63, h = bh & 7;
    kbuf[((size_t)bh * S1P + SRC) * HD + hd] = f2bf(bk[h * HD + hd]);
    vtbuf[((size_t)bh * HD + hd) * S1P + SRC] = f2bf(bv[h * HD + hd]);
    for (int s = SRC + 1; s < S1P; ++s) {
        kbuf[((size_t)bh * S1P + s) * HD + hd] = 0;
        vtbuf[((size_t)bh * HD + hd) * S1P + s] = 0;
    }
}

// vbuf [bh][s][hd] -> vtbuf [bh][hd][s]
__global__ __launch_bounds__(256) void transpose_v(const unsigned short* __restrict__ vbuf,
    unsigned short* __restrict__ vtbuf)
{
    __shared__ __align__(16) unsigned short T[64][72];
    const int tid = threadIdx.x;
    const int s0  = blockIdx.x << 6;
    const int bh  = blockIdx.y;
#pragma unroll
    for (int i = 0; i < 2; ++i) {
        const int idx = tid + (i << 8);
        const int s = idx >> 3, q = (idx & 7) << 3;
        *(int4*)&T[s][q] = *(const int4*)&vbuf[((size_t)bh * SRC + s0 + s) * HD + q];
    }
    __syncthreads();
#pragma unroll
    for (int i = 0; i < 2; ++i) {
        const int idx = tid + (i << 8);
        const int hd = idx >> 3, sq = (idx & 7) << 3;
        unsigned short tmp[8];
#pragma unroll
        for (int j = 0; j < 8; ++j) tmp[j] = T[sq + j][hd];
        *(int4*)&vtbuf[((size_t)bh * HD + hd) * S1P + s0 + sq] = *(int4*)tmp;
    }
}

// ---------------------------------------------------------------------------
// Fused single-pass attention. One block = 16 target rows of one (b,h).
// Phase 1 (chunk-parallel, no barriers): QK^T via MFMA with K fragments read
//   directly from L2/L3-resident kbuf; exp(score - mask) -> unnormalized P
//   kept resident in LDS (bf16, padded stride); per-row sums accumulated.
// Phase 2: cross-wave sum reduction -> linv[16].
// Phase 3 (barrier-free): PV from LDS-P (A-frags, conflict-free ds_read_b128)
//   with V^T fragments direct from global; scale by linv at the end (softmax
//   denominator commutes with the linear PV). Normalized fp32 attn written
//   straight from LDS-P.
// Replaces stats_kernel + attn_pv: one QK^T instead of two, no K/V LDS
// staging, 2 barriers total instead of 99.
// ---------------------------------------------------------------------------
__global__ __launch_bounds__(256, 2) void attn_fused(
    const unsigned short* __restrict__ qbh,
    const unsigned short* __restrict__ kbuf,
    const unsigned short* __restrict__ vtbuf,
    const int* __restrict__ kpm,
    float* __restrict__ attn, unsigned short* __restrict__ ctx)
{
    __shared__ __align__(16) unsigned short P[16][PW];   // 67.8 KB
    __shared__ float mf[S1P];                            // 8.4 KB
    __shared__ float sums[4][16];
    __shared__ float linv[16];
    const int tid = threadIdx.x;
    const int t0  = blockIdx.x << 4;
    const int bh  = blockIdx.y;
    const int bb  = bh >> 3;
    const int w = tid >> 6, lane = tid & 63, c = lane & 15, quad = lane >> 4;

    // mask vector for all padded source columns
    for (int s = tid; s < S1P; s += 256)
        mf[s] = (s < SRC) ? (kpm[bb * SRC + s] ? 3e38f : 0.f)
                          : ((s == SRC) ? 0.f : 3e38f);

    // Q A-fragments for this block's 16 rows (held in registers all kernel)
    const unsigned short* qr = &qbh[((size_t)bh * TGT + t0 + c) * HD + (quad << 3)];
    short8 qa0 = *(const short8*)qr;
    short8 qa1 = *(const short8*)(qr + 32);

    __syncthreads();

    // ---- phase 1: QK^T + exp, chunk-parallel across waves ----
    float rs[4] = {0.f, 0.f, 0.f, 0.f};
    for (int ch = w; ch < NCH; ch += 4) {
        const int s0 = ch << 6;
        floatx4 sc[4] = {};
#pragma unroll
        for (int n = 0; n < 4; ++n) {
            const unsigned short* kr =
                &kbuf[((size_t)bh * S1P + s0 + (n << 4) + c) * HD + (quad << 3)];
            short8 b0 = *(const short8*)kr;
            short8 b1 = *(const short8*)(kr + 32);
            sc[n] = __builtin_amdgcn_mfma_f32_16x16x32_bf16(qa0, b0, sc[n], 0, 0, 0);
            sc[n] = __builtin_amdgcn_mfma_f32_16x16x32_bf16(qa1, b1, sc[n], 0, 0, 0);
        }
#pragma unroll
        for (int n = 0; n < 4; ++n) {
            const float m = mf[s0 + (n << 4) + c];
#pragma unroll
            for (int reg = 0; reg < 4; ++reg) {
                const float p = __expf(sc[n][reg] - m);
                rs[reg] += p;
                P[(quad << 2) + reg][s0 + (n << 4) + c] = f2bf(p);
            }
        }
    }

    // ---- phase 2: row-sum reduction (over c lanes, then over waves) ----
#pragma unroll
    for (int reg = 0; reg < 4; ++reg) {
        float v = rs[reg];
        v += __shfl_xor(v, 1); v += __shfl_xor(v, 2);
        v += __shfl_xor(v, 4); v += __shfl_xor(v, 8);
        rs[reg] = v;
    }
    if (c == 0) {
#pragma unroll
        for (int reg = 0; reg < 4; ++reg)
            sums[w][(quad << 2) + reg] = rs[reg];
    }
    __syncthreads();
    if (tid < 16)
        linv[tid] = 1.0f / (sums[0][tid] + sums[1][tid] + sums[2][tid] + sums[3][tid]);
    __syncthreads();

    // ---- phase 3a: PV (wave w owns hd columns w*16..w*16+15) ----
    floatx4 ca = {};
#pragma unroll 6
    for (int kc = 0; kc < 66; ++kc) {
        short8 a = *(const short8*)&P[c][(kc << 5) + (quad << 3)];
        short8 b = *(const short8*)&vtbuf[((size_t)bh * HD + (w << 4) + c) * S1P
                                          + (kc << 5) + (quad << 3)];
        ca = __builtin_amdgcn_mfma_f32_16x16x32_bf16(a, b, ca, 0, 0, 0);
    }
#pragma unroll
    for (int reg = 0; reg < 4; ++reg) {
        const int t = t0 + (quad << 2) + reg;
        ctx[((size_t)bh * TGT + t) * HD + (w << 4) + c] =
            f2bf(ca[reg] * linv[(quad << 2) + reg]);
    }

    // ---- phase 3b: normalized fp32 attn output straight from LDS-P ----
    for (int ch = w; ch < NCH; ch += 4) {
        const int s0 = ch << 6;
        if (ch < 32) {
#pragma unroll
            for (int r = 0; r < 16; ++r) {
                const float p =
                    __uint_as_float((unsigned)P[r][s0 + lane] << 16) * linv[r];
                attn[((size_t)bh * TGT + t0 + r) * S1 + s0 + lane] = p;
            }
        } else if (lane < 16) {   // last chunk: only s == 2048 is a real column
            const float p =
                __uint_as_float((unsigned)P[lane][2048] << 16) * linv[lane];
            attn[((size_t)bh * TGT + t0 + lane) * S1 + 2048] = p;
        }
    }
}

// ---------------------------------------------------------------------------
// out-projection: out[r][e] = ctx_row(r) . W[e][:] + bias[e]  (fp32 out)
// ---------------------------------------------------------------------------
__global__ __launch_bounds__(256) void outproj_gemm(const unsigned short* __restrict__ ctx,
    const unsigned short* __restrict__ W, const float* __restrict__ bias,
    float* __restrict__ out)
{
    __shared__ __align__(16) unsigned short As[128][72];
    __shared__ __align__(16) unsigned short Bs[64][72];
    const int tid = threadIdx.x;
    const int c0  = blockIdx.x << 6;
    const int r0  = blockIdx.y << 7;
    const int w   = tid >> 6, lane = tid & 63, c = lane & 15, quad = lane >> 4;
    floatx4 acc[2][4] = {};
    for (int k0 = 0; k0 < E; k0 += 64) {
        const int h = k0 >> 6;
#pragma unroll
        for (int i = 0; i < 4; ++i) {
            const int idx = tid + (i << 8);
            const int r = idx >> 3, q = (idx & 7) << 3;
            const int rg = r0 + r, t = rg >> 4, b = rg & 15;
            *(int4*)&As[r][q] = *(const int4*)&ctx[((size_t)(b * H + h) * TGT + t) * HD + q];
        }
#pragma unroll
        for (int i = 0; i < 2; ++i) {
            const int idx = tid + (i << 8);
            const int r = idx >> 3, q = (idx & 7) << 3;
            *(int4*)&Bs[r][q] = *(const int4*)&W[(size_t)(c0 + r) * E + k0 + q];
        }
        __syncthreads();
#pragma unroll
        for (int kh = 0; kh < 2; ++kh) {
            short8 a0 = *(const short8*)&As[(w << 5) + c][(kh << 5) + (quad << 3)];
            short8 a1 = *(const short8*)&As[(w << 5) + 16 + c][(kh << 5) + (quad << 3)];
#pragma unroll
            for (int n = 0; n < 4; ++n) {
                short8 b = *(const short8*)&Bs[(n << 4) + c][(kh << 5) + (quad << 3)];
                acc[0][n] = __builtin_amdgcn_mfma_f32_16x16x32_bf16(a0, b, acc[0][n], 0, 0, 0);
                acc[1][n] = __builtin_amdgcn_mfma_f32_16x16x32_bf16(a1, b, acc[1][n], 0, 0, 0);
            }
        }
        __syncthreads();
    }
#pragma unroll
    for (int mt = 0; mt < 2; ++mt) {
#pragma unroll
        for (int reg = 0; reg < 4; ++reg) {
            const int rg = r0 + (w << 5) + (mt << 4) + (quad << 2) + reg;
#pragma unroll
            for (int n = 0; n < 4; ++n) {
                const int col = c0 + (n << 4) + c;
                out[(size_t)rg * E + col] = acc[mt][n][reg] + bias[col];
            }
        }
    }
}

extern "C" void kernel_launch(void* const* d_in, const int* in_sizes, int n_in,
                              void* d_out, int out_size, void* d_ws, size_t ws_size,
                              hipStream_t stream)
{
    const float* query  = (const float*)d_in[0];
    const float* key    = (const float*)d_in[1];
    const float* value  = (const float*)d_in[2];
    const float* ipw    = (const float*)d_in[3];
    const float* ipb    = (const float*)d_in[4];
    const float* bias_k = (const float*)d_in[5];
    const float* bias_v = (const float*)d_in[6];
    const float* opw    = (const float*)d_in[7];
    const float* opb    = (const float*)d_in[8];
    const int*   kpm    = (const int*)d_in[9];

    float* out  = (float*)d_out;
    float* attn = out + (size_t)TGT * NB * E;                 // 128*512*2049 fp32

    // scratch bf16 buffers that die before the fused attention live in attn
    unsigned short* k_bf = (unsigned short*)attn;             // key converted  [32768][512]
    unsigned short* v_bf = k_bf + (size_t)16777216;           // value converted
    unsigned short* vbuf = v_bf + (size_t)16777216;           // V proj [bh][s][hd]

    char* ws = (char*)d_ws;
    unsigned short* q_bf  = (unsigned short*)ws;                       // [8192][512]
    unsigned short* wi_bf = q_bf  + (size_t)4194304;                   // [3E][E]
    unsigned short* wo_bf = wi_bf + (size_t)786432;                    // [E][E]
    unsigned short* qbh   = wo_bf + (size_t)262144;                    // [bh][t][hd]
    unsigned short* kbuf  = qbh   + (size_t)4194304;                   // [bh][S1P][hd]
    unsigned short* vtbuf = kbuf  + (size_t)17301504;                  // [bh][hd][S1P]
    unsigned short* ctx   = vtbuf + (size_t)17301504;                  // [bh][t][hd]

    cvt_bf16<<<dim3(2048), 256, 0, stream>>>(query, q_bf, 524288);
    cvt_bf16<<<dim3(8192), 256, 0, stream>>>(key,   k_bf, 2097152);
    cvt_bf16<<<dim3(8192), 256, 0, stream>>>(value, v_bf, 2097152);
    cvt_bf16<<<dim3(384),  256, 0, stream>>>(ipw,   wi_bf, 98304);
    cvt_bf16<<<dim3(128),  256, 0, stream>>>(opw,   wo_bf, 32768);

    proj_gemm<<<dim3(8, 64),  256, 0, stream>>>(q_bf, wi_bf,          ipb,         qbh,  TGT, 0.125f);
    proj_gemm<<<dim3(8, 256), 256, 0, stream>>>(k_bf, wi_bf + 262144, ipb + E,     kbuf, S1P, 1.0f);
    proj_gemm<<<dim3(8, 256), 256, 0, stream>>>(v_bf, wi_bf + 524288, ipb + 2 * E, vbuf, SRC, 1.0f);

    fill_bias<<<dim3(32), 256, 0, stream>>>(bias_k, bias_v, kbuf, vtbuf);
    transpose_v<<<dim3(32, 128), 256, 0, stream>>>(vbuf, vtbuf);

    attn_fused<<<dim3(32, 128), 256, 0, stream>>>(qbh, kbuf, vtbuf, kpm, attn, ctx);
    outproj_gemm<<<dim3(8, 64), 256, 0, stream>>>(ctx, wo_bf, opb, out);
}

// Round 2
// 1094.272 us; speedup vs baseline: 1.0109x; 1.0109x over previous
//
#include <hip/hip_runtime.h>

#define E    512
#define H    8
#define HD   64
#define TGT  512
#define SRC  2048
#define S1   2049
#define S1P  2112     // padded source length (33 chunks of 64)
#define NB   16
#define BH   128
#define NCH  33
#define PW   2120     // P row stride in shorts: 4240 B = 16B-aligned, bank-uniform

typedef __attribute__((ext_vector_type(8))) short short8;
typedef __attribute__((ext_vector_type(4))) float floatx4;

__device__ __forceinline__ unsigned short f2bf(float x) {
    unsigned u = __float_as_uint(x);
    u = (u + 0x7FFF + ((u >> 16) & 1)) >> 16;   // round-to-nearest-even
    return (unsigned short)u;
}

// ---------------------------------------------------------------------------
// fp32 -> bf16 conversion, 8 elements/thread
// ---------------------------------------------------------------------------
__global__ __launch_bounds__(256) void cvt_bf16(const float* __restrict__ src,
    unsigned short* __restrict__ dst, const int n8)
{
    const int i = blockIdx.x * 256 + threadIdx.x;
    if (i >= n8) return;
    const float4 f0 = ((const float4*)src)[(size_t)i * 2];
    const float4 f1 = ((const float4*)src)[(size_t)i * 2 + 1];
    unsigned short o[8] = {f2bf(f0.x), f2bf(f0.y), f2bf(f0.z), f2bf(f0.w),
                           f2bf(f1.x), f2bf(f1.y), f2bf(f1.z), f2bf(f1.w)};
    ((int4*)dst)[i] = *(int4*)o;
}

// ---------------------------------------------------------------------------
// in-projection: Y = (X @ W^T + bias) * scale, output bf16 in [b*H+h][row][hd]
// ---------------------------------------------------------------------------
__global__ __launch_bounds__(256) void proj_gemm(const unsigned short* __restrict__ X,
    const unsigned short* __restrict__ W, const float* __restrict__ bias,
    unsigned short* __restrict__ Y, const int ld, const float scale)
{
    __shared__ __align__(16) unsigned short As[128][72];
    __shared__ __align__(16) unsigned short Bs[64][72];
    const int tid  = threadIdx.x;
    const int c0   = blockIdx.x << 6;
    const int r0   = blockIdx.y << 7;
    const int w    = tid >> 6, lane = tid & 63, c = lane & 15, quad = lane >> 4;
    floatx4 acc[2][4] = {};
    for (int k0 = 0; k0 < E; k0 += 64) {
#pragma unroll
        for (int i = 0; i < 4; ++i) {
            const int idx = tid + (i << 8);
            const int r = idx >> 3, q = (idx & 7) << 3;
            *(int4*)&As[r][q] = *(const int4*)&X[(size_t)(r0 + r) * E + k0 + q];
        }
#pragma unroll
        for (int i = 0; i < 2; ++i) {
            const int idx = tid + (i << 8);
            const int r = idx >> 3, q = (idx & 7) << 3;
            *(int4*)&Bs[r][q] = *(const int4*)&W[(size_t)(c0 + r) * E + k0 + q];
        }
        __syncthreads();
#pragma unroll
        for (int kh = 0; kh < 2; ++kh) {
            short8 a0 = *(const short8*)&As[(w << 5) + c][(kh << 5) + (quad << 3)];
            short8 a1 = *(const short8*)&As[(w << 5) + 16 + c][(kh << 5) + (quad << 3)];
#pragma unroll
            for (int n = 0; n < 4; ++n) {
                short8 b = *(const short8*)&Bs[(n << 4) + c][(kh << 5) + (quad << 3)];
                acc[0][n] = __builtin_amdgcn_mfma_f32_16x16x32_bf16(a0, b, acc[0][n], 0, 0, 0);
                acc[1][n] = __builtin_amdgcn_mfma_f32_16x16x32_bf16(a1, b, acc[1][n], 0, 0, 0);
            }
        }
        __syncthreads();
    }
#pragma unroll
    for (int mt = 0; mt < 2; ++mt) {
#pragma unroll
        for (int reg = 0; reg < 4; ++reg) {
            const int rg = r0 + (w << 5) + (mt << 4) + (quad << 2) + reg;
            const int t = rg >> 4, b = rg & 15;
#pragma unroll
            for (int n = 0; n < 4; ++n) {
                const int col = c0 + (n << 4) + c;
                const int h = col >> 6, hd = col & 63;
                const float v = (acc[mt][n][reg] + bias[col]) * scale;
                Y[((size_t)(b * H + h) * ld + t) * HD + hd] = f2bf(v);
            }
        }
    }
}

// kbuf[bh][2048][hd] = bias_k; vtbuf[bh][hd][2048] = bias_v.
// Also zero the pad tail (s in [2049,2112)) of both buffers.
__global__ void fill_bias(const float* __restrict__ bk, const float* __restrict__ bv,
                          unsigned short* __restrict__ kbuf, unsigned short* __restrict__ vtbuf)
{
    const int idx = blockIdx.x * 256 + threadIdx.x;   // 0..8191
    const int bh = idx >> 6, hd = idx & 63, h = bh & 7;
    kbuf[((size_t)bh * S1P + SRC) * HD + hd] = f2bf(bk[h * HD + hd]);
    vtbuf[((size_t)bh * HD + hd) * S1P + SRC] = f2bf(bv[h * HD + hd]);
    for (int s = SRC + 1; s < S1P; ++s) {
        kbuf[((size_t)bh * S1P + s) * HD + hd] = 0;
        vtbuf[((size_t)bh * HD + hd) * S1P + s] = 0;
    }
}

// vbuf [bh][s][hd] -> vtbuf [bh][hd][s]
__global__ __launch_bounds__(256) void transpose_v(const unsigned short* __restrict__ vbuf,
    unsigned short* __restrict__ vtbuf)
{
    __shared__ __align__(16) unsigned short T[64][72];
    const int tid = threadIdx.x;
    const int s0  = blockIdx.x << 6;
    const int bh  = blockIdx.y;
#pragma unroll
    for (int i = 0; i < 2; ++i) {
        const int idx = tid + (i << 8);
        const int s = idx >> 3, q = (idx & 7) << 3;
        *(int4*)&T[s][q] = *(const int4*)&vbuf[((size_t)bh * SRC + s0 + s) * HD + q];
    }
    __syncthreads();
#pragma unroll
    for (int i = 0; i < 2; ++i) {
        const int idx = tid + (i << 8);
        const int hd = idx >> 3, sq = (idx & 7) << 3;
        unsigned short tmp[8];
#pragma unroll
        for (int j = 0; j < 8; ++j) tmp[j] = T[sq + j][hd];
        *(int4*)&vtbuf[((size_t)bh * HD + hd) * S1P + s0 + sq] = *(int4*)tmp;
    }
}

// ---------------------------------------------------------------------------
// Fused single-pass attention, latency-pipelined version.
//  - phase 1: QK^T + exp with depth-1 register prefetch of K fragments
//  - phase 2: cross-wave row-sum reduction -> linv
//  - phase 3: PV (two interleaved accumulator chains, V prefetch) with the
//    normalized fp32 attn stores interleaved into the MFMA loop
//  - attn/ctx written with non-temporal stores so the 550 MB write stream
//    does not evict L3-resident K/V (FETCH_SIZE was 3.2x unique inputs)
// ---------------------------------------------------------------------------
__global__ __launch_bounds__(256, 2) void attn_fused(
    const unsigned short* __restrict__ qbh,
    const unsigned short* __restrict__ kbuf,
    const unsigned short* __restrict__ vtbuf,
    const int* __restrict__ kpm,
    float* __restrict__ attn, unsigned short* __restrict__ ctx)
{
    __shared__ __align__(16) unsigned short P[16][PW];   // 67.8 KB
    __shared__ float mf[S1P];                            // 8.4 KB
    __shared__ float sums[4][16];
    __shared__ float linv[16];
    const int tid = threadIdx.x;
    const int t0  = blockIdx.x << 4;
    const int bh  = blockIdx.y;
    const int bb  = bh >> 3;
    const int w = tid >> 6, lane = tid & 63, c = lane & 15, quad = lane >> 4;

    // mask vector for all padded source columns
    for (int s = tid; s < S1P; s += 256)
        mf[s] = (s < SRC) ? (kpm[bb * SRC + s] ? 3e38f : 0.f)
                          : ((s == SRC) ? 0.f : 3e38f);

    // Q A-fragments for this block's 16 rows (held in registers all kernel)
    const unsigned short* qr = &qbh[((size_t)bh * TGT + t0 + c) * HD + (quad << 3)];
    short8 qa0 = *(const short8*)qr;
    short8 qa1 = *(const short8*)(qr + 32);

#define LOADK(D0, D1, CH) do {                                                  \
        const unsigned short* kb_ = &kbuf[((size_t)bh * S1P + ((CH) << 6)) * HD]; \
        _Pragma("unroll")                                                       \
        for (int n_ = 0; n_ < 4; ++n_) {                                        \
            const unsigned short* kr_ = kb_ + ((n_ << 4) + c) * HD + (quad << 3); \
            D0[n_] = *(const short8*)kr_;                                       \
            D1[n_] = *(const short8*)(kr_ + 32);                                \
        }                                                                       \
    } while (0)

#define QK_COMPUTE(CH, B0, B1) do {                                             \
        const int s0_ = (CH) << 6;                                              \
        floatx4 sc_[4] = {};                                                    \
        _Pragma("unroll")                                                       \
        for (int n_ = 0; n_ < 4; ++n_) {                                        \
            sc_[n_] = __builtin_amdgcn_mfma_f32_16x16x32_bf16(qa0, B0[n_], sc_[n_], 0, 0, 0); \
            sc_[n_] = __builtin_amdgcn_mfma_f32_16x16x32_bf16(qa1, B1[n_], sc_[n_], 0, 0, 0); \
        }                                                                       \
        _Pragma("unroll")                                                       \
        for (int n_ = 0; n_ < 4; ++n_) {                                        \
            const float m_ = mf[s0_ + (n_ << 4) + c];                           \
            _Pragma("unroll")                                                   \
            for (int rg_ = 0; rg_ < 4; ++rg_) {                                 \
                const float p_ = __expf(sc_[n_][rg_] - m_);                     \
                rs[rg_] += p_;                                                  \
                P[(quad << 2) + rg_][s0_ + (n_ << 4) + c] = f2bf(p_);           \
            }                                                                   \
        }                                                                       \
    } while (0)

    // issue the first K-chunk load before the mask barrier
    short8 kb0[4], kb1[4];
    LOADK(kb0, kb1, w);

    __syncthreads();

    // ---- phase 1: QK^T + exp, chunk-parallel across waves, prefetch depth 1
    float rs[4] = {0.f, 0.f, 0.f, 0.f};
    int ch;
    for (ch = w; ch + 4 < NCH; ch += 4) {
        short8 nb0[4], nb1[4];
        LOADK(nb0, nb1, ch + 4);          // in flight during compute below
        QK_COMPUTE(ch, kb0, kb1);
#pragma unroll
        for (int n = 0; n < 4; ++n) { kb0[n] = nb0[n]; kb1[n] = nb1[n]; }
    }
    QK_COMPUTE(ch, kb0, kb1);             // tail chunk (no prefetch)

    // ---- phase 2: row-sum reduction (over c lanes, then over waves) ----
#pragma unroll
    for (int reg = 0; reg < 4; ++reg) {
        float v = rs[reg];
        v += __shfl_xor(v, 1); v += __shfl_xor(v, 2);
        v += __shfl_xor(v, 4); v += __shfl_xor(v, 8);
        rs[reg] = v;
    }
    if (c == 0) {
#pragma unroll
        for (int reg = 0; reg < 4; ++reg)
            sums[w][(quad << 2) + reg] = rs[reg];
    }
    __syncthreads();
    if (tid < 16)
        linv[tid] = 1.0f / (sums[0][tid] + sums[1][tid] + sums[2][tid] + sums[3][tid]);
    __syncthreads();

    // ---- phase 3: PV + interleaved normalized fp32 attn stores ----
#define STORE_CHUNK(CH) do {                                                    \
        if ((CH) < 32) {                                                        \
            _Pragma("unroll")                                                   \
            for (int r_ = 0; r_ < 16; ++r_) {                                   \
                const float p_ = __uint_as_float(                               \
                    (unsigned)P[r_][((CH) << 6) + lane] << 16) * linv[r_];      \
                __builtin_nontemporal_store(p_,                                 \
                    &attn[((size_t)bh * TGT + t0 + r_) * S1 + ((CH) << 6) + lane]); \
            }                                                                   \
        } else if (lane < 16) {                                                 \
            const float p_ = __uint_as_float(                                   \
                (unsigned)P[lane][2048] << 16) * linv[lane];                    \
            __builtin_nontemporal_store(p_,                                     \
                &attn[((size_t)bh * TGT + t0 + lane) * S1 + 2048]);             \
        }                                                                       \
    } while (0)

    const unsigned short* vrow = &vtbuf[((size_t)bh * HD + (w << 4) + c) * S1P];
    floatx4 ca0 = {}, ca1 = {};
    short8 vb0 = *(const short8*)&vrow[(quad << 3)];
    short8 vb1 = *(const short8*)&vrow[32 + (quad << 3)];
#pragma unroll 4
    for (int kc = 0; kc < 32; ++kc) {
        short8 nv0 = *(const short8*)&vrow[((kc + 1) << 6) + (quad << 3)];
        short8 nv1 = *(const short8*)&vrow[((kc + 1) << 6) + 32 + (quad << 3)];
        short8 a0 = *(const short8*)&P[c][(kc << 6) + (quad << 3)];
        short8 a1 = *(const short8*)&P[c][(kc << 6) + 32 + (quad << 3)];
        ca0 = __builtin_amdgcn_mfma_f32_16x16x32_bf16(a0, vb0, ca0, 0, 0, 0);
        ca1 = __builtin_amdgcn_mfma_f32_16x16x32_bf16(a1, vb1, ca1, 0, 0, 0);
        if ((kc & 3) == w) STORE_CHUNK(kc);
        vb0 = nv0; vb1 = nv1;
    }
    {   // tail chunk 32
        short8 a0 = *(const short8*)&P[c][(32 << 6) + (quad << 3)];
        short8 a1 = *(const short8*)&P[c][(32 << 6) + 32 + (quad << 3)];
        ca0 = __builtin_amdgcn_mfma_f32_16x16x32_bf16(a0, vb0, ca0, 0, 0, 0);
        ca1 = __builtin_amdgcn_mfma_f32_16x16x32_bf16(a1, vb1, ca1, 0, 0, 0);
        if (w == 0) STORE_CHUNK(32);
    }

#pragma unroll
    for (int reg = 0; reg < 4; ++reg) {
        const int t = t0 + (quad << 2) + reg;
        const float v = (ca0[reg] + ca1[reg]) * linv[(quad << 2) + reg];
        __builtin_nontemporal_store(f2bf(v),
            &ctx[((size_t)bh * TGT + t) * HD + (w << 4) + c]);
    }
#undef LOADK
#undef QK_COMPUTE
#undef STORE_CHUNK
}

// ---------------------------------------------------------------------------
// out-projection: out[r][e] = ctx_row(r) . W[e][:] + bias[e]  (fp32 out)
// ---------------------------------------------------------------------------
__global__ __launch_bounds__(256) void outproj_gemm(const unsigned short* __restrict__ ctx,
    const unsigned short* __restrict__ W, const float* __restrict__ bias,
    float* __restrict__ out)
{
    __shared__ __align__(16) unsigned short As[128][72];
    __shared__ __align__(16) unsigned short Bs[64][72];
    const int tid = threadIdx.x;
    const int c0  = blockIdx.x << 6;
    const int r0  = blockIdx.y << 7;
    const int w   = tid >> 6, lane = tid & 63, c = lane & 15, quad = lane >> 4;
    floatx4 acc[2][4] = {};
    for (int k0 = 0; k0 < E; k0 += 64) {
        const int h = k0 >> 6;
#pragma unroll
        for (int i = 0; i < 4; ++i) {
            const int idx = tid + (i << 8);
            const int r = idx >> 3, q = (idx & 7) << 3;
            const int rg = r0 + r, t = rg >> 4, b = rg & 15;
            *(int4*)&As[r][q] = *(const int4*)&ctx[((size_t)(b * H + h) * TGT + t) * HD + q];
        }
#pragma unroll
        for (int i = 0; i < 2; ++i) {
            const int idx = tid + (i << 8);
            const int r = idx >> 3, q = (idx & 7) << 3;
            *(int4*)&Bs[r][q] = *(const int4*)&W[(size_t)(c0 + r) * E + k0 + q];
        }
        __syncthreads();
#pragma unroll
        for (int kh = 0; kh < 2; ++kh) {
            short8 a0 = *(const short8*)&As[(w << 5) + c][(kh << 5) + (quad << 3)];
            short8 a1 = *(const short8*)&As[(w << 5) + 16 + c][(kh << 5) + (quad << 3)];
#pragma unroll
            for (int n = 0; n < 4; ++n) {
                short8 b = *(const short8*)&Bs[(n << 4) + c][(kh << 5) + (quad << 3)];
                acc[0][n] = __builtin_amdgcn_mfma_f32_16x16x32_bf16(a0, b, acc[0][n], 0, 0, 0);
                acc[1][n] = __builtin_amdgcn_mfma_f32_16x16x32_bf16(a1, b, acc[1][n], 0, 0, 0);
            }
        }
        __syncthreads();
    }
#pragma unroll
    for (int mt = 0; mt < 2; ++mt) {
#pragma unroll
        for (int reg = 0; reg < 4; ++reg) {
            const int rg = r0 + (w << 5) + (mt << 4) + (quad << 2) + reg;
#pragma unroll
            for (int n = 0; n < 4; ++n) {
                const int col = c0 + (n << 4) + c;
                out[(size_t)rg * E + col] = acc[mt][n][reg] + bias[col];
            }
        }
    }
}

extern "C" void kernel_launch(void* const* d_in, const int* in_sizes, int n_in,
                              void* d_out, int out_size, void* d_ws, size_t ws_size,
                              hipStream_t stream)
{
    const float* query  = (const float*)d_in[0];
    const float* key    = (const float*)d_in[1];
    const float* value  = (const float*)d_in[2];
    const float* ipw    = (const float*)d_in[3];
    const float* ipb    = (const float*)d_in[4];
    const float* bias_k = (const float*)d_in[5];
    const float* bias_v = (const float*)d_in[6];
    const float* opw    = (const float*)d_in[7];
    const float* opb    = (const float*)d_in[8];
    const int*   kpm    = (const int*)d_in[9];

    float* out  = (float*)d_out;
    float* attn = out + (size_t)TGT * NB * E;                 // 128*512*2049 fp32

    // scratch bf16 buffers that die before the fused attention live in attn
    unsigned short* k_bf = (unsigned short*)attn;             // key converted  [32768][512]
    unsigned short* v_bf = k_bf + (size_t)16777216;           // value converted
    unsigned short* vbuf = v_bf + (size_t)16777216;           // V proj [bh][s][hd]

    char* ws = (char*)d_ws;
    unsigned short* q_bf  = (unsigned short*)ws;                       // [8192][512]
    unsigned short* wi_bf = q_bf  + (size_t)4194304;                   // [3E][E]
    unsigned short* wo_bf = wi_bf + (size_t)786432;                    // [E][E]
    unsigned short* qbh   = wo_bf + (size_t)262144;                    // [bh][t][hd]
    unsigned short* kbuf  = qbh   + (size_t)4194304;                   // [bh][S1P][hd]
    unsigned short* vtbuf = kbuf  + (size_t)17301504;                  // [bh][hd][S1P]
    unsigned short* ctx   = vtbuf + (size_t)17301504;                  // [bh][t][hd]

    cvt_bf16<<<dim3(2048), 256, 0, stream>>>(query, q_bf, 524288);
    cvt_bf16<<<dim3(8192), 256, 0, stream>>>(key,   k_bf, 2097152);
    cvt_bf16<<<dim3(8192), 256, 0, stream>>>(value, v_bf, 2097152);
    cvt_bf16<<<dim3(384),  256, 0, stream>>>(ipw,   wi_bf, 98304);
    cvt_bf16<<<dim3(128),  256, 0, stream>>>(opw,   wo_bf, 32768);

    proj_gemm<<<dim3(8, 64),  256, 0, stream>>>(q_bf, wi_bf,          ipb,         qbh,  TGT, 0.125f);
    proj_gemm<<<dim3(8, 256), 256, 0, stream>>>(k_bf, wi_bf + 262144, ipb + E,     kbuf, S1P, 1.0f);
    proj_gemm<<<dim3(8, 256), 256, 0, stream>>>(v_bf, wi_bf + 524288, ipb + 2 * E, vbuf, SRC, 1.0f);

    fill_bias<<<dim3(32), 256, 0, stream>>>(bias_k, bias_v, kbuf, vtbuf);
    transpose_v<<<dim3(32, 128), 256, 0, stream>>>(vbuf, vtbuf);

    attn_fused<<<dim3(32, 128), 256, 0, stream>>>(qbh, kbuf, vtbuf, kpm, attn, ctx);
    outproj_gemm<<<dim3(8, 64), 256, 0, stream>>>(ctx, wo_bf, opb, out);
}

// Round 3
// 1082.980 us; speedup vs baseline: 1.0214x; 1.0104x over previous
//
#include <hip/hip_runtime.h>

#define E    512
#define H    8
#define HD   64
#define TGT  512
#define SRC  2048
#define S1   2049
#define S1P  2112     // padded source length (33 chunks of 64)
#define NB   16
#define BH   128
#define NCH  33
#define PW   2120     // P row stride in shorts: 4240 B = 16B-aligned, bank-uniform

typedef __attribute__((ext_vector_type(8))) short short8;
typedef __attribute__((ext_vector_type(4))) float floatx4;

__device__ __forceinline__ unsigned short f2bf(float x) {
    unsigned u = __float_as_uint(x);
    u = (u + 0x7FFF + ((u >> 16) & 1)) >> 16;   // round-to-nearest-even
    return (unsigned short)u;
}

// ---------------------------------------------------------------------------
// fp32 -> bf16 conversion, 8 elements/thread
// ---------------------------------------------------------------------------
__global__ __launch_bounds__(256) void cvt_bf16(const float* __restrict__ src,
    unsigned short* __restrict__ dst, const int n8)
{
    const int i = blockIdx.x * 256 + threadIdx.x;
    if (i >= n8) return;
    const float4 f0 = ((const float4*)src)[(size_t)i * 2];
    const float4 f1 = ((const float4*)src)[(size_t)i * 2 + 1];
    unsigned short o[8] = {f2bf(f0.x), f2bf(f0.y), f2bf(f0.z), f2bf(f0.w),
                           f2bf(f1.x), f2bf(f1.y), f2bf(f1.z), f2bf(f1.w)};
    ((int4*)dst)[i] = *(int4*)o;
}

// ---------------------------------------------------------------------------
// in-projection: Y = (X @ W^T + bias) * scale, output bf16 in [b*H+h][row][hd]
// ---------------------------------------------------------------------------
__global__ __launch_bounds__(256) void proj_gemm(const unsigned short* __restrict__ X,
    const unsigned short* __restrict__ W, const float* __restrict__ bias,
    unsigned short* __restrict__ Y, const int ld, const float scale)
{
    __shared__ __align__(16) unsigned short As[128][72];
    __shared__ __align__(16) unsigned short Bs[64][72];
    const int tid  = threadIdx.x;
    const int c0   = blockIdx.x << 6;
    const int r0   = blockIdx.y << 7;
    const int w    = tid >> 6, lane = tid & 63, c = lane & 15, quad = lane >> 4;
    floatx4 acc[2][4] = {};
    for (int k0 = 0; k0 < E; k0 += 64) {
#pragma unroll
        for (int i = 0; i < 4; ++i) {
            const int idx = tid + (i << 8);
            const int r = idx >> 3, q = (idx & 7) << 3;
            *(int4*)&As[r][q] = *(const int4*)&X[(size_t)(r0 + r) * E + k0 + q];
        }
#pragma unroll
        for (int i = 0; i < 2; ++i) {
            const int idx = tid + (i << 8);
            const int r = idx >> 3, q = (idx & 7) << 3;
            *(int4*)&Bs[r][q] = *(const int4*)&W[(size_t)(c0 + r) * E + k0 + q];
        }
        __syncthreads();
#pragma unroll
        for (int kh = 0; kh < 2; ++kh) {
            short8 a0 = *(const short8*)&As[(w << 5) + c][(kh << 5) + (quad << 3)];
            short8 a1 = *(const short8*)&As[(w << 5) + 16 + c][(kh << 5) + (quad << 3)];
#pragma unroll
            for (int n = 0; n < 4; ++n) {
                short8 b = *(const short8*)&Bs[(n << 4) + c][(kh << 5) + (quad << 3)];
                acc[0][n] = __builtin_amdgcn_mfma_f32_16x16x32_bf16(a0, b, acc[0][n], 0, 0, 0);
                acc[1][n] = __builtin_amdgcn_mfma_f32_16x16x32_bf16(a1, b, acc[1][n], 0, 0, 0);
            }
        }
        __syncthreads();
    }
#pragma unroll
    for (int mt = 0; mt < 2; ++mt) {
#pragma unroll
        for (int reg = 0; reg < 4; ++reg) {
            const int rg = r0 + (w << 5) + (mt << 4) + (quad << 2) + reg;
            const int t = rg >> 4, b = rg & 15;
#pragma unroll
            for (int n = 0; n < 4; ++n) {
                const int col = c0 + (n << 4) + c;
                const int h = col >> 6, hd = col & 63;
                const float v = (acc[mt][n][reg] + bias[col]) * scale;
                Y[((size_t)(b * H + h) * ld + t) * HD + hd] = f2bf(v);
            }
        }
    }
}

// ---------------------------------------------------------------------------
// bias columns + pad-tail zeroing, fully parallel (one store per thread).
// old version ran on 32 blocks with 126 scattered stores/thread.
// ---------------------------------------------------------------------------
#define FB_BIAS  8192
#define FB_KPAD  64512                       // 128 bh * 504 int4 (63 rows * 64 hd)
#define FB_VPAD  516096                      // 128 bh * 64 hd * 63 s
__global__ __launch_bounds__(256) void fill_bias(const float* __restrict__ bk,
    const float* __restrict__ bv,
    unsigned short* __restrict__ kbuf, unsigned short* __restrict__ vtbuf)
{
    const int idx = blockIdx.x * 256 + threadIdx.x;
    if (idx < FB_BIAS) {
        const int bh = idx >> 6, hd = idx & 63, h = bh & 7;
        kbuf[((size_t)bh * S1P + SRC) * HD + hd] = f2bf(bk[h * HD + hd]);
        vtbuf[((size_t)bh * HD + hd) * S1P + SRC] = f2bf(bv[h * HD + hd]);
    } else if (idx < FB_BIAS + FB_KPAD) {
        const int i = idx - FB_BIAS;
        const int bh = i / 504, o = i % 504;
        const int4 z = {0, 0, 0, 0};
        ((int4*)&kbuf[((size_t)bh * S1P + S1) * HD])[o] = z;
    } else if (idx < FB_BIAS + FB_KPAD + FB_VPAD) {
        const int i = idx - FB_BIAS - FB_KPAD;
        const int bh = i / 4032, r = i % 4032;
        const int hd = r / 63, s = S1 + r % 63;
        vtbuf[((size_t)bh * HD + hd) * S1P + s] = 0;
    }
}

// vbuf [bh][s][hd] -> vtbuf [bh][hd][s]
__global__ __launch_bounds__(256) void transpose_v(const unsigned short* __restrict__ vbuf,
    unsigned short* __restrict__ vtbuf)
{
    __shared__ __align__(16) unsigned short T[64][72];
    const int tid = threadIdx.x;
    const int s0  = blockIdx.x << 6;
    const int bh  = blockIdx.y;
#pragma unroll
    for (int i = 0; i < 2; ++i) {
        const int idx = tid + (i << 8);
        const int s = idx >> 3, q = (idx & 7) << 3;
        *(int4*)&T[s][q] = *(const int4*)&vbuf[((size_t)bh * SRC + s0 + s) * HD + q];
    }
    __syncthreads();
#pragma unroll
    for (int i = 0; i < 2; ++i) {
        const int idx = tid + (i << 8);
        const int hd = idx >> 3, sq = (idx & 7) << 3;
        unsigned short tmp[8];
#pragma unroll
        for (int j = 0; j < 8; ++j) tmp[j] = T[sq + j][hd];
        *(int4*)&vtbuf[((size_t)bh * HD + hd) * S1P + s0 + sq] = *(int4*)tmp;
    }
}

// ---------------------------------------------------------------------------
// Fused single-pass attention, 512 threads / 8 waves per block.
// 2 blocks/CU (LDS 72.8 KB) -> 16 waves/CU = 50% occupancy (2x the 256-thread
// version): the kernel was latency-bound with every pipe <30% busy.
//  - phase 1: 33 chunks split over 8 waves; K frags + mask prefetched depth-1
//  - phase 2: cross-wave row-sum reduction -> linv
//  - phase 3a: PV split (4 hd-slices x 2 K-halves) + LDS cross-reduce
//  - phase 3b: normalized fp32 attn stores, 8-way wave-parallel
// ---------------------------------------------------------------------------
__global__ __launch_bounds__(512, 4) void attn_fused(
    const unsigned short* __restrict__ qbh,
    const unsigned short* __restrict__ kbuf,
    const unsigned short* __restrict__ vtbuf,
    const int* __restrict__ kpm,
    float* __restrict__ attn, unsigned short* __restrict__ ctx)
{
    __shared__ __align__(16) unsigned short P[16][PW];   // 67.84 KB
    __shared__ float cpart[16][68];                      // 4.25 KB
    __shared__ float sums[8][16];
    __shared__ float linv[16];
    const int tid = threadIdx.x;
    const int t0  = blockIdx.x << 4;
    const int bh  = blockIdx.y;
    const int bb  = bh >> 3;
    const int w = tid >> 6, lane = tid & 63, c = lane & 15, quad = lane >> 4;

    // Q A-fragments for this block's 16 rows (same for every wave)
    const unsigned short* qr = &qbh[((size_t)bh * TGT + t0 + c) * HD + (quad << 3)];
    short8 qa0 = *(const short8*)qr;
    short8 qa1 = *(const short8*)(qr + 32);

#define LOADK(D0, D1, M, CH) do {                                               \
        const unsigned short* kb_ = &kbuf[((size_t)bh * S1P + ((CH) << 6)) * HD]; \
        _Pragma("unroll")                                                       \
        for (int n_ = 0; n_ < 4; ++n_) {                                        \
            const unsigned short* kr_ = kb_ + ((n_ << 4) + c) * HD + (quad << 3); \
            D0[n_] = *(const short8*)kr_;                                       \
            D1[n_] = *(const short8*)(kr_ + 32);                                \
        }                                                                       \
        _Pragma("unroll")                                                       \
        for (int n_ = 0; n_ < 4; ++n_) {                                        \
            const int s_ = ((CH) << 6) + (n_ << 4) + c;                         \
            M[n_] = (s_ < SRC) ? (kpm[bb * SRC + s_] ? 3e38f : 0.f)             \
                               : ((s_ == SRC) ? 0.f : 3e38f);                   \
        }                                                                       \
    } while (0)

#define QK_COMPUTE(CH, B0, B1, M) do {                                          \
        const int s0_ = (CH) << 6;                                              \
        floatx4 sc_[4] = {};                                                    \
        _Pragma("unroll")                                                       \
        for (int n_ = 0; n_ < 4; ++n_) {                                        \
            sc_[n_] = __builtin_amdgcn_mfma_f32_16x16x32_bf16(qa0, B0[n_], sc_[n_], 0, 0, 0); \
            sc_[n_] = __builtin_amdgcn_mfma_f32_16x16x32_bf16(qa1, B1[n_], sc_[n_], 0, 0, 0); \
        }                                                                       \
        _Pragma("unroll")                                                       \
        for (int n_ = 0; n_ < 4; ++n_) {                                        \
            _Pragma("unroll")                                                   \
            for (int rg_ = 0; rg_ < 4; ++rg_) {                                 \
                const float p_ = __expf(sc_[n_][rg_] - M[n_]);                  \
                rs[rg_] += p_;                                                  \
                P[(quad << 2) + rg_][s0_ + (n_ << 4) + c] = f2bf(p_);           \
            }                                                                   \
        }                                                                       \
    } while (0)

    // ---- phase 1: QK^T + exp, 33 chunks over 8 waves, prefetch depth 1 ----
    float rs[4] = {0.f, 0.f, 0.f, 0.f};
    short8 kb0[4], kb1[4];
    float mk[4];
    LOADK(kb0, kb1, mk, w);
    int ch;
    for (ch = w; ch + 8 < NCH; ch += 8) {
        short8 nb0[4], nb1[4];
        float nm[4];
        LOADK(nb0, nb1, nm, ch + 8);
        QK_COMPUTE(ch, kb0, kb1, mk);
#pragma unroll
        for (int n = 0; n < 4; ++n) { kb0[n] = nb0[n]; kb1[n] = nb1[n]; mk[n] = nm[n]; }
    }
    QK_COMPUTE(ch, kb0, kb1, mk);

    // ---- phase 2: row-sum reduction (over c lanes, then over 8 waves) ----
#pragma unroll
    for (int reg = 0; reg < 4; ++reg) {
        float v = rs[reg];
        v += __shfl_xor(v, 1); v += __shfl_xor(v, 2);
        v += __shfl_xor(v, 4); v += __shfl_xor(v, 8);
        rs[reg] = v;
    }
    if (c == 0) {
#pragma unroll
        for (int reg = 0; reg < 4; ++reg)
            sums[w][(quad << 2) + reg] = rs[reg];
    }
    __syncthreads();
    if (tid < 16) {
        float s = 0.f;
#pragma unroll
        for (int i = 0; i < 8; ++i) s += sums[i][tid];
        linv[tid] = 1.0f / s;
    }
    __syncthreads();

    // ---- phase 3a: PV. wave -> (hd-slice hs, K-half kh2); LDS cross-reduce
    const int hs = w & 3, kh2 = w >> 2;
    const int base = kh2 * 1056;             // column offset (33 units of 32)
    const unsigned short* vrow = &vtbuf[((size_t)bh * HD + (hs << 4) + c) * S1P + base];
    const unsigned short* prow = &P[c][base];
    floatx4 ca0 = {}, ca1 = {};
#pragma unroll 4
    for (int kc = 0; kc < 16; ++kc) {
        short8 a0 = *(const short8*)&prow[(kc << 6) + (quad << 3)];
        short8 a1 = *(const short8*)&prow[(kc << 6) + 32 + (quad << 3)];
        short8 b0 = *(const short8*)&vrow[(kc << 6) + (quad << 3)];
        short8 b1 = *(const short8*)&vrow[(kc << 6) + 32 + (quad << 3)];
        ca0 = __builtin_amdgcn_mfma_f32_16x16x32_bf16(a0, b0, ca0, 0, 0, 0);
        ca1 = __builtin_amdgcn_mfma_f32_16x16x32_bf16(a1, b1, ca1, 0, 0, 0);
    }
    {   // 33rd 32-column unit of this half
        short8 a = *(const short8*)&prow[1024 + (quad << 3)];
        short8 b = *(const short8*)&vrow[1024 + (quad << 3)];
        ca0 = __builtin_amdgcn_mfma_f32_16x16x32_bf16(a, b, ca0, 0, 0, 0);
    }
    if (kh2 == 1) {
#pragma unroll
        for (int reg = 0; reg < 4; ++reg)
            cpart[(quad << 2) + reg][(hs << 4) + c] = ca0[reg] + ca1[reg];
    }
    __syncthreads();
    if (kh2 == 0) {
#pragma unroll
        for (int reg = 0; reg < 4; ++reg) {
            const int row = (quad << 2) + reg;
            const float v = (ca0[reg] + ca1[reg] + cpart[row][(hs << 4) + c]) * linv[row];
            ctx[((size_t)bh * TGT + t0 + row) * HD + (hs << 4) + c] = f2bf(v);
        }
    }

    // ---- phase 3b: normalized fp32 attn stores, 8-way wave-parallel ----
    for (int c2 = w; c2 < NCH; c2 += 8) {
        const int s0 = c2 << 6;
        if (c2 < 32) {
#pragma unroll
            for (int r = 0; r < 16; ++r) {
                const float p =
                    __uint_as_float((unsigned)P[r][s0 + lane] << 16) * linv[r];
                attn[((size_t)bh * TGT + t0 + r) * S1 + s0 + lane] = p;
            }
        } else if (lane < 16) {
            const float p =
                __uint_as_float((unsigned)P[lane][2048] << 16) * linv[lane];
            attn[((size_t)bh * TGT + t0 + lane) * S1 + 2048] = p;
        }
    }
#undef LOADK
#undef QK_COMPUTE
}

// ---------------------------------------------------------------------------
// out-projection: out[r][e] = ctx_row(r) . W[e][:] + bias[e]  (fp32 out)
// ---------------------------------------------------------------------------
__global__ __launch_bounds__(256) void outproj_gemm(const unsigned short* __restrict__ ctx,
    const unsigned short* __restrict__ W, const float* __restrict__ bias,
    float* __restrict__ out)
{
    __shared__ __align__(16) unsigned short As[128][72];
    __shared__ __align__(16) unsigned short Bs[64][72];
    const int tid = threadIdx.x;
    const int c0  = blockIdx.x << 6;
    const int r0  = blockIdx.y << 7;
    const int w   = tid >> 6, lane = tid & 63, c = lane & 15, quad = lane >> 4;
    floatx4 acc[2][4] = {};
    for (int k0 = 0; k0 < E; k0 += 64) {
        const int h = k0 >> 6;
#pragma unroll
        for (int i = 0; i < 4; ++i) {
            const int idx = tid + (i << 8);
            const int r = idx >> 3, q = (idx & 7) << 3;
            const int rg = r0 + r, t = rg >> 4, b = rg & 15;
            *(int4*)&As[r][q] = *(const int4*)&ctx[((size_t)(b * H + h) * TGT + t) * HD + q];
        }
#pragma unroll
        for (int i = 0; i < 2; ++i) {
            const int idx = tid + (i << 8);
            const int r = idx >> 3, q = (idx & 7) << 3;
            *(int4*)&Bs[r][q] = *(const int4*)&W[(size_t)(c0 + r) * E + k0 + q];
        }
        __syncthreads();
#pragma unroll
        for (int kh = 0; kh < 2; ++kh) {
            short8 a0 = *(const short8*)&As[(w << 5) + c][(kh << 5) + (quad << 3)];
            short8 a1 = *(const short8*)&As[(w << 5) + 16 + c][(kh << 5) + (quad << 3)];
#pragma unroll
            for (int n = 0; n < 4; ++n) {
                short8 b = *(const short8*)&Bs[(n << 4) + c][(kh << 5) + (quad << 3)];
                acc[0][n] = __builtin_amdgcn_mfma_f32_16x16x32_bf16(a0, b, acc[0][n], 0, 0, 0);
                acc[1][n] = __builtin_amdgcn_mfma_f32_16x16x32_bf16(a1, b, acc[1][n], 0, 0, 0);
            }
        }
        __syncthreads();
    }
#pragma unroll
    for (int mt = 0; mt < 2; ++mt) {
#pragma unroll
        for (int reg = 0; reg < 4; ++reg) {
            const int rg = r0 + (w << 5) + (mt << 4) + (quad << 2) + reg;
#pragma unroll
            for (int n = 0; n < 4; ++n) {
                const int col = c0 + (n << 4) + c;
                out[(size_t)rg * E + col] = acc[mt][n][reg] + bias[col];
            }
        }
    }
}

extern "C" void kernel_launch(void* const* d_in, const int* in_sizes, int n_in,
                              void* d_out, int out_size, void* d_ws, size_t ws_size,
                              hipStream_t stream)
{
    const float* query  = (const float*)d_in[0];
    const float* key    = (const float*)d_in[1];
    const float* value  = (const float*)d_in[2];
    const float* ipw    = (const float*)d_in[3];
    const float* ipb    = (const float*)d_in[4];
    const float* bias_k = (const float*)d_in[5];
    const float* bias_v = (const float*)d_in[6];
    const float* opw    = (const float*)d_in[7];
    const float* opb    = (const float*)d_in[8];
    const int*   kpm    = (const int*)d_in[9];

    float* out  = (float*)d_out;
    float* attn = out + (size_t)TGT * NB * E;                 // 128*512*2049 fp32

    // scratch bf16 buffers that die before the fused attention live in attn
    unsigned short* k_bf = (unsigned short*)attn;             // key converted  [32768][512]
    unsigned short* v_bf = k_bf + (size_t)16777216;           // value converted
    unsigned short* vbuf = v_bf + (size_t)16777216;           // V proj [bh][s][hd]

    char* ws = (char*)d_ws;
    unsigned short* q_bf  = (unsigned short*)ws;                       // [8192][512]
    unsigned short* wi_bf = q_bf  + (size_t)4194304;                   // [3E][E]
    unsigned short* wo_bf = wi_bf + (size_t)786432;                    // [E][E]
    unsigned short* qbh   = wo_bf + (size_t)262144;                    // [bh][t][hd]
    unsigned short* kbuf  = qbh   + (size_t)4194304;                   // [bh][S1P][hd]
    unsigned short* vtbuf = kbuf  + (size_t)17301504;                  // [bh][hd][S1P]
    unsigned short* ctx   = vtbuf + (size_t)17301504;                  // [bh][t][hd]

    cvt_bf16<<<dim3(2048), 256, 0, stream>>>(query, q_bf, 524288);
    cvt_bf16<<<dim3(8192), 256, 0, stream>>>(key,   k_bf, 2097152);
    cvt_bf16<<<dim3(8192), 256, 0, stream>>>(value, v_bf, 2097152);
    cvt_bf16<<<dim3(384),  256, 0, stream>>>(ipw,   wi_bf, 98304);
    cvt_bf16<<<dim3(128),  256, 0, stream>>>(opw,   wo_bf, 32768);

    proj_gemm<<<dim3(8, 64),  256, 0, stream>>>(q_bf, wi_bf,          ipb,         qbh,  TGT, 0.125f);
    proj_gemm<<<dim3(8, 256), 256, 0, stream>>>(k_bf, wi_bf + 262144, ipb + E,     kbuf, S1P, 1.0f);
    proj_gemm<<<dim3(8, 256), 256, 0, stream>>>(v_bf, wi_bf + 524288, ipb + 2 * E, vbuf, SRC, 1.0f);

    fill_bias<<<dim3(2300), 256, 0, stream>>>(bias_k, bias_v, kbuf, vtbuf);
    transpose_v<<<dim3(32, 128), 256, 0, stream>>>(vbuf, vtbuf);

    attn_fused<<<dim3(32, 128), 512, 0, stream>>>(qbh, kbuf, vtbuf, kpm, attn, ctx);
    outproj_gemm<<<dim3(8, 64), 256, 0, stream>>>(ctx, wo_bf, opb, out);
}